// Round 8
// baseline (436.336 us; speedup 1.0000x reference)
//
#include <hip/hip_runtime.h>

#define HD 64
#define BN_EPS 1e-5f

typedef unsigned int u32;
typedef __attribute__((ext_vector_type(8))) short bfrag;
typedef __attribute__((ext_vector_type(4))) float ffrag;

__device__ __forceinline__ unsigned tobf(float x) {
    unsigned u = __float_as_uint(x);
    return (u + 0x7fffu + ((u >> 16) & 1u)) >> 16;
}
__device__ __forceinline__ float bf_lo(unsigned u) { return __uint_as_float(u << 16); }
__device__ __forceinline__ float bf_hi(unsigned u) { return __uint_as_float(u & 0xffff0000u); }

// ---------- CSR construction (rows padded to 4: slot0=self, pads->node N) ----------

#define FILL_SLAB 4096

// XCD-partitioned degree count: each partition's deg window is L2-resident ->
// atomics stay local to the XCD instead of 1M cross-fabric atomics.
__global__ void k_deg(const int* __restrict__ dst, int* __restrict__ deg, int E) {
    int tid = threadIdx.x;
    int part = blockIdx.x & 7;
    int base = (blockIdx.x >> 3) * FILL_SLAB;
    int end = min(base + FILL_SLAB, E);
    for (int e = base + tid; e < end; e += 256) {
        int d = __builtin_nontemporal_load(&dst[e]);
        if (((d >> 12) & 7) == part) atomicAdd(&deg[d], 1);
    }
}

// inclusive scan of padded degree (256/block) + dinv + hWs zero-row init
__global__ void k_scan1(const int* __restrict__ deg, int* __restrict__ incl,
                        int* __restrict__ bsums, float* __restrict__ dinv,
                        unsigned* __restrict__ hWs, int N) {
    __shared__ int s[256];
    int tid = threadIdx.x;
    int i = blockIdx.x * 256 + tid;
    if (blockIdx.x == 0 && tid < 32) hWs[(size_t)N * 32 + tid] = 0u;  // zero row
    int d = (i < N) ? deg[i] : 0;
    int pd = (i < N) ? ((d + 4) & ~3) : 0;  // roundup(deg+1, 4)
    s[tid] = pd;
    __syncthreads();
    for (int off = 1; off < 256; off <<= 1) {
        int t = (tid >= off) ? s[tid - off] : 0;
        __syncthreads();
        s[tid] += t;
        __syncthreads();
    }
    if (i < N) {
        incl[i] = s[tid];
        dinv[i] = rsqrtf((float)(d + 1));
    }
    if (tid == 255) bsums[blockIdx.x] = s[255];
}

// rowp from incl + per-block prefix of bsums (reduction, no separate scan pass);
// also writes self edge into slot0 and pad slots -> N
__global__ void k_scan3(int* __restrict__ rowp, const int* __restrict__ deg,
                        const int* __restrict__ incl, const int* __restrict__ bsums,
                        int* __restrict__ ed, int N, int nb) {
    __shared__ float red[256];
    int tid = threadIdx.x;
    int b = blockIdx.x;
    float psum = 0.f;
    for (int t = tid; t < b; t += 256) psum += (float)bsums[t];
    red[tid] = psum;
    __syncthreads();
    for (int off = 128; off > 0; off >>= 1) {
        if (tid < off) red[tid] += red[tid + off];
        __syncthreads();
    }
    int bpre = (int)red[0];
    int i = b * 256 + tid;
    if (i < N) {
        int d = deg[i];
        int pd = (d + 4) & ~3;
        int rv = incl[i] - pd + bpre;  // exclusive global offset
        rowp[i] = rv;
        ed[rv] = i;  // self edge in slot 0
        for (int k = d + 1; k < pd; k++) ed[rv + k] = N;  // pads -> zero row
        if (i == N - 1) rowp[N] = rv + pd;
    }
}

// XCD-partitioned scatter: block handles partition (blockIdx&7) of a slab of edges.
// ed-write window and cur-atomic window are both L2-resident per partition.
// NT loads keep the streamed edge arrays from evicting the scatter window.
// Per-graph counts fused (unique gid).
__global__ void k_fill(const int* __restrict__ src, const int* __restrict__ dst,
                       const int* __restrict__ rowp, int* __restrict__ cur,
                       int* __restrict__ ed, const int* __restrict__ batch,
                       int* __restrict__ cnt, int E, int N, int G) {
    int tid = threadIdx.x;
    int gid = blockIdx.x * 256 + tid;
    if (gid < G) {
        int g = gid;
        int lo = 0, hi = N;
        while (lo < hi) { int mid = (lo + hi) >> 1; if (batch[mid] < g) lo = mid + 1; else hi = mid; }
        int lo2 = lo, hi2 = N;
        while (lo2 < hi2) { int mid = (lo2 + hi2) >> 1; if (batch[mid] < g + 1) lo2 = mid + 1; else hi2 = mid; }
        cnt[g] = lo2 - lo;
    }
    int part = blockIdx.x & 7;
    int base = (blockIdx.x >> 3) * FILL_SLAB;
    int end = min(base + FILL_SLAB, E);
    for (int e = base + tid; e < end; e += 256) {
        int d = __builtin_nontemporal_load(&dst[e]);
        if (((d >> 12) & 7) == part) {
            int s = __builtin_nontemporal_load(&src[e]);
            int pos = rowp[d] + 1 + atomicAdd(&cur[d], 1);
            ed[pos] = s;
        }
    }
}

// ---------- MFMA gemm: hWs[i][f] = bf16( dinv[i]*(sum_k A[i][k]*W[f][k] + cb[f]) ) ----------
template<int FP32IN>
__global__ __launch_bounds__(256) void k_gemm2(const void* __restrict__ Aptr,
                                               const void* __restrict__ Wptr,
                                               const float* __restrict__ cb,
                                               const float* __restrict__ dinv,
                                               unsigned short* __restrict__ hWs,
                                               int N, int ntiles) {
    int lane = threadIdx.x & 63;
    int m = lane & 15, quad = lane >> 4;
    bfrag wf[4][2];
    if (FP32IN) {
        const float* W = (const float*)Wptr;
#pragma unroll
        for (int ft = 0; ft < 4; ft++)
#pragma unroll
            for (int kf = 0; kf < 2; kf++) {
                const float4* p4 = (const float4*)(W + (ft * 16 + m) * HD + kf * 32 + quad * 8);
                float4 x0 = p4[0], x1 = p4[1];
                union { unsigned u[4]; bfrag b; } r;
                r.u[0] = tobf(x0.x) | (tobf(x0.y) << 16);
                r.u[1] = tobf(x0.z) | (tobf(x0.w) << 16);
                r.u[2] = tobf(x1.x) | (tobf(x1.y) << 16);
                r.u[3] = tobf(x1.z) | (tobf(x1.w) << 16);
                wf[ft][kf] = r.b;
            }
    } else {
        const unsigned short* W = (const unsigned short*)Wptr;
#pragma unroll
        for (int ft = 0; ft < 4; ft++)
#pragma unroll
            for (int kf = 0; kf < 2; kf++)
                wf[ft][kf] = *(const bfrag*)(W + (ft * 16 + m) * HD + kf * 32 + quad * 8);
    }
    float cbv[4];
#pragma unroll
    for (int ft = 0; ft < 4; ft++) cbv[ft] = cb ? cb[ft * 16 + m] : 0.f;

    int wid = (blockIdx.x * blockDim.x + threadIdx.x) >> 6;
    int nw = (gridDim.x * blockDim.x) >> 6;
    for (int tile = wid; tile < ntiles; tile += nw) {
        int arow = min(tile * 16 + m, N - 1);
        bfrag a0, a1;
        if (FP32IN) {
            const float4* p4 = (const float4*)((const float*)Aptr + (size_t)arow * HD + quad * 8);
            float4 x0 = p4[0], x1 = p4[1], y0 = p4[8], y1 = p4[9];
            union { unsigned u[4]; bfrag b; } r0, r1;
            r0.u[0] = tobf(x0.x) | (tobf(x0.y) << 16);
            r0.u[1] = tobf(x0.z) | (tobf(x0.w) << 16);
            r0.u[2] = tobf(x1.x) | (tobf(x1.y) << 16);
            r0.u[3] = tobf(x1.z) | (tobf(x1.w) << 16);
            r1.u[0] = tobf(y0.x) | (tobf(y0.y) << 16);
            r1.u[1] = tobf(y0.z) | (tobf(y0.w) << 16);
            r1.u[2] = tobf(y1.x) | (tobf(y1.y) << 16);
            r1.u[3] = tobf(y1.z) | (tobf(y1.w) << 16);
            a0 = r0.b; a1 = r1.b;
        } else {
            const unsigned short* p = (const unsigned short*)Aptr + (size_t)arow * HD + quad * 8;
            a0 = *(const bfrag*)p;
            a1 = *(const bfrag*)(p + 32);
        }
        ffrag acc[4];
#pragma unroll
        for (int ft = 0; ft < 4; ft++) {
            acc[ft] = (ffrag){0.f, 0.f, 0.f, 0.f};
            acc[ft] = __builtin_amdgcn_mfma_f32_16x16x32_bf16(a0, wf[ft][0], acc[ft], 0, 0, 0);
            acc[ft] = __builtin_amdgcn_mfma_f32_16x16x32_bf16(a1, wf[ft][1], acc[ft], 0, 0, 0);
        }
        int r0n = tile * 16 + quad * 4;
        float dv[4];
#pragma unroll
        for (int r = 0; r < 4; r++) dv[r] = dinv[min(r0n + r, N - 1)];
#pragma unroll
        for (int ft = 0; ft < 4; ft++)
#pragma unroll
            for (int r = 0; r < 4; r++) {
                int nrow = r0n + r;
                if (nrow < N) {
                    float v = (acc[ft][r] + cbv[ft]) * dv[r];
                    hWs[(size_t)nrow * HD + ft * 16 + m] = (unsigned short)tobf(v);
                }
            }
    }
}

// ---------- aggregation v7: 64-slot stages, pad-4 rows, 4-slot consume groups ----------
// Gather/staging identical to v5/v6 (8x global_load_lds per 64-slot stage, dbuf).
// Consume: 4-slot groups (rows padded to multiples of 4 -> groups never straddle
// nodes): 2 batched LDS reads + 4 adds + ONE wave-uniform rem check per group --
// r6's proven cheap structure at half group width (no branchy while-loop).
// lane=hf*32+m handles features (2m,2m+1) of slot-parity hf; halves combined at
// node end via shfl_xor(32). Node metadata pre-staged one-node-per-lane.
// LDS 66KB/block -> 2 blocks/CU.
__global__ __launch_bounds__(256) void k_agg(const int* __restrict__ rowp,
                                             const int* __restrict__ ed,
                                             const float* __restrict__ dinv,
                                             const unsigned* __restrict__ hWs,
                                             const float* __restrict__ bias,
                                             const int* __restrict__ batch,
                                             void* __restrict__ outp, int outBf,
                                             float* __restrict__ stats,
                                             float* __restrict__ praw,
                                             int N, int chunk,
                                             const float* __restrict__ gam,
                                             const float* __restrict__ bet,
                                             float* __restrict__ ss,
                                             const float* __restrict__ Wnext,
                                             unsigned* __restrict__ Wfb,
                                             float* __restrict__ cf,
                                             float invN, int* __restrict__ ticket) {
    __shared__ u32 sbuf[4][2][2048];   // per-wave double-buffered stage: 64 slots x 32 words
    int tid = threadIdx.x;
    int lane = tid & 63;
    int hf = lane >> 5;
    int m = lane & 31;
    int lsel = lane >> 3;   // slot sub-index within an 8-slot gather
    int fsel = lane & 7;    // 16B sub-row handled by this lane
    int wv = tid >> 6;
    int wid = blockIdx.x * 4 + wv;
    int i0 = wid * chunk, i1 = min(i0 + chunk, N);
    const uint4* hW4 = (const uint4*)hWs;
    float b0 = bias[2 * m], b1 = bias[2 * m + 1];
    float bs0 = 0.f, bs1 = 0.f, bq0 = 0.f, bq1 = 0.f;
    int curb = -1;
    float p0 = 0.f, p1 = 0.f;
    if (i0 < N) {
        // pre-stage per-node metadata: lane l holds node i0+l (chunk <= 63)
        int idx = i0 + lane;
        int rowv = rowp[min(idx, N)];
        float dinvv = dinv[min(idx, N - 1)];
        int batchv = batch[min(idx, N - 1)];
        int s0g = __shfl(rowv, 0);
        int send = __shfl(rowv, i1 - i0);
        int i = i0, ln = 0;
        int rem = (__shfl(rowv, 1) - s0g) >> 2;  // 4-slot groups left in node i
        float acc0 = 0.f, acc1 = 0.f;
        int nst = (send - s0g + 63) >> 6;        // 64-slot stages
        int sb = s0g;
        // prologue: ids + gathers for stage 0 (one id per lane)
        int eidx;
        { int id = sb + lane; eidx = (id < send) ? __builtin_nontemporal_load(&ed[id]) : N; }
#pragma unroll
        for (int j = 0; j < 8; j++) {
            int sj = __shfl(eidx, j * 8 + lsel);
            __builtin_amdgcn_global_load_lds(
                (const __attribute__((address_space(1))) u32*)(hW4 + (size_t)sj * 8 + fsel),
                (__attribute__((address_space(3))) u32*)(&sbuf[wv][0][j * 256]),
                16, 0, 0);
        }
        int eidxN = N;
        if (nst > 1) { int id = sb + 64 + lane; eidxN = (id < send) ? __builtin_nontemporal_load(&ed[id]) : N; }
        for (int t = 0; t < nst; t++) {
            int cb = t & 1;
            // stage t's DMA (and eidxN) complete; compiler must not hoist LDS reads above
            asm volatile("s_waitcnt vmcnt(0)" ::: "memory");
            __builtin_amdgcn_sched_barrier(0);
            if (t + 1 < nst) {
#pragma unroll
                for (int j = 0; j < 8; j++) {
                    int sj = __shfl(eidxN, j * 8 + lsel);
                    __builtin_amdgcn_global_load_lds(
                        (const __attribute__((address_space(1))) u32*)(hW4 + (size_t)sj * 8 + fsel),
                        (__attribute__((address_space(3))) u32*)(&sbuf[wv][cb ^ 1][j * 256]),
                        16, 0, 0);
                }
                if (t + 2 < nst) { int id = sb + 128 + lane; eidxN = (id < send) ? __builtin_nontemporal_load(&ed[id]) : N; }
            }
            const u32* cur = &sbuf[wv][cb][0];
            int ng = min(16, (send - sb) >> 2);  // 4-slot groups this stage
            for (int g = 0; g < ng; g++) {
                u32 u0 = cur[(g * 4 + hf) * 32 + m];
                u32 u1 = cur[(g * 4 + 2 + hf) * 32 + m];
                acc0 += bf_lo(u0) + bf_lo(u1);
                acc1 += bf_hi(u0) + bf_hi(u1);
                if (--rem == 0) {  // node i complete (wave-uniform)
                    float s0 = acc0 + __shfl_xor(acc0, 32);
                    float s1 = acc1 + __shfl_xor(acc1, 32);
                    float di = __shfl(dinvv, ln);   // register shuffle, no load
                    int b = __shfl(batchv, ln);
                    float h0 = fmaxf(fmaf(di, s0, b0), 0.f);
                    float h1 = fmaxf(fmaf(di, s1, b1), 0.f);
                    if (lane < 32) {
                        if (outBf) ((unsigned*)outp)[(size_t)i * 32 + m] = tobf(h0) | (tobf(h1) << 16);
                        else ((float2*)outp)[(size_t)i * 32 + m] = make_float2(h0, h1);
                        bs0 += h0; bs1 += h1;
                        bq0 = fmaf(h0, h0, bq0); bq1 = fmaf(h1, h1, bq1);
                        if (b != curb) {
                            if (curb >= 0) {
                                atomicAdd(&praw[(size_t)curb * HD + 2 * m], p0);
                                atomicAdd(&praw[(size_t)curb * HD + 2 * m + 1], p1);
                            }
                            curb = b; p0 = h0; p1 = h1;
                        } else { p0 += h0; p1 += h1; }
                    }
                    i++; ln++;
                    rem = (i < i1) ? ((__shfl(rowv, ln + 1) - __shfl(rowv, ln)) >> 2)
                                   : 0x3fffffff;  // sentinel: never triggers past range
                    acc0 = 0.f; acc1 = 0.f;
                }
            }
            sb += 64;
        }
    }
    if (lane < 32 && curb >= 0) {
        atomicAdd(&praw[(size_t)curb * HD + 2 * m], p0);
        atomicAdd(&praw[(size_t)curb * HD + 2 * m + 1], p1);
    }
    __shared__ float r1s[4][HD], r2s[4][HD];
    if (lane < 32) {
        r1s[wv][2 * m] = bs0; r1s[wv][2 * m + 1] = bs1;
        r2s[wv][2 * m] = bq0; r2s[wv][2 * m + 1] = bq1;
    }
    __syncthreads();
    if (tid < HD) {
        atomicAdd(&stats[tid], r1s[0][tid] + r1s[1][tid] + r1s[2][tid] + r1s[3][tid]);
        atomicAdd(&stats[HD + tid], r2s[0][tid] + r2s[1][tid] + r2s[2][tid] + r2s[3][tid]);
    }
    // ---- last block: BN finalize + fold into next layer's weights ----
    __shared__ int lastFlag;
    __syncthreads();  // drain this block's stats atomics
    if (tid == 0) {
        __threadfence();
        lastFlag = (atomicAdd(ticket, 1) == (int)gridDim.x - 1) ? 1 : 0;
    }
    __syncthreads();
    if (lastFlag) {
        __shared__ float lss[128];
        __shared__ float cpart[HD][4];
        if (tid < HD) {
            float s1v = atomicAdd(&stats[tid], 0.f);       // coherent read
            float s2v = atomicAdd(&stats[HD + tid], 0.f);
            float mean = s1v * invN;
            float var = s2v * invN - mean * mean;
            float sc = gam[tid] * rsqrtf(var + BN_EPS);
            float sh = bet[tid] - mean * sc;
            ss[tid] = sc; ss[64 + tid] = sh;
            lss[tid] = sc; lss[64 + tid] = sh;
        }
        __syncthreads();
        if (Wnext) {   // 256 threads: 64 rows x 4 partials, float4 weight loads
            int r = tid >> 2, qs = (tid & 3) * 8;
            const float4* W4 = (const float4*)(Wnext + r * HD + 2 * qs);
            float c = 0.f;
#pragma unroll
            for (int t = 0; t < 4; t++) {
                float4 w = W4[t];
                int q = qs + 2 * t;
                Wfb[r * 32 + q]     = tobf(w.x * lss[2 * q])     | (tobf(w.y * lss[2 * q + 1]) << 16);
                Wfb[r * 32 + q + 1] = tobf(w.z * lss[2 * q + 2]) | (tobf(w.w * lss[2 * q + 3]) << 16);
                c = fmaf(lss[64 + 2 * q], w.x, c);
                c = fmaf(lss[64 + 2 * q + 1], w.y, c);
                c = fmaf(lss[64 + 2 * q + 2], w.z, c);
                c = fmaf(lss[64 + 2 * q + 3], w.w, c);
            }
            cpart[r][tid & 3] = c;
            __syncthreads();
            if (tid < HD)
                cf[tid] = cpart[tid][0] + cpart[tid][1] + cpart[tid][2] + cpart[tid][3];
        }
    }
}

// fused: normalize final h in place (float4) + pool finalize
__global__ __launch_bounds__(256) void k_fin(float* __restrict__ h,
                                             const float* __restrict__ ss_all,
                                             const float* __restrict__ praw,
                                             const int* __restrict__ cnt,
                                             float* __restrict__ pool,
                                             int nquads, int G) {
    int nb1 = (nquads + 255) >> 8;
    if ((int)blockIdx.x < nb1) {
        int idx = blockIdx.x * 256 + threadIdx.x;
        if (idx >= nquads) return;
        const float* ss = ss_all + 2 * 128;
        float4* h4 = (float4*)h;
        float4 v = h4[idx];
        int f0 = (idx * 4) & 63;
        v.x = fmaf(v.x, ss[f0 + 0], ss[64 + f0 + 0]);
        v.y = fmaf(v.y, ss[f0 + 1], ss[64 + f0 + 1]);
        v.z = fmaf(v.z, ss[f0 + 2], ss[64 + f0 + 2]);
        v.w = fmaf(v.w, ss[f0 + 3], ss[64 + f0 + 3]);
        h4[idx] = v;
    } else {
        int idx = (blockIdx.x - nb1) * 256 + threadIdx.x;
        if (idx >= G * 192) return;
        int g = idx / 192;
        int r = idx - g * 192;
        int l = r >> 6;
        int f = r & 63;
        const float* ss = ss_all + l * 128;
        float v = praw[((size_t)l * G + g) * HD + f];
        pool[idx] = fmaf(ss[f], v, (float)cnt[g] * ss[64 + f]);
    }
}

extern "C" void kernel_launch(void* const* d_in, const int* in_sizes, int n_in,
                              void* d_out, int out_size, void* d_ws, size_t ws_size,
                              hipStream_t stream) {
    const int N = in_sizes[0] / HD;             // 100000
    const int E = in_sizes[1] / 2;              // 1000000
    const int G = (out_size - N * HD) / 192;    // 512

    const float* x = (const float*)d_in[0];
    const int* ei = (const int*)d_in[1];
    const int* srcA = ei;
    const int* dstA = ei + E;
    const int* batch = (const int*)d_in[2];
    const float* W[3]    = {(const float*)d_in[3], (const float*)d_in[7],  (const float*)d_in[11]};
    const float* bias[3] = {(const float*)d_in[4], (const float*)d_in[8],  (const float*)d_in[12]};
    const float* gam[3]  = {(const float*)d_in[5], (const float*)d_in[9],  (const float*)d_in[13]};
    const float* bet[3]  = {(const float*)d_in[6], (const float*)d_in[10], (const float*)d_in[14]};

    char* ws = (char*)d_ws;
    size_t off = 0;
    auto alloc = [&](size_t bytes) -> void* {
        void* p = ws + off;
        off = (off + bytes + 255) & ~(size_t)255;
        return p;
    };
    // zero-region (single memset): deg, cur, stats, tickets, praw
    int* deg     = (int*)alloc((size_t)N * 4);
    int* cur     = (int*)alloc((size_t)N * 4);
    float* stats = (float*)alloc(3 * 128 * 4);
    int* tickets = (int*)alloc(3 * 4);
    float* praw  = (float*)alloc((size_t)3 * G * HD * 4);
    size_t zbytes = off;
    float* dinv  = (float*)alloc((size_t)N * 4);
    int* rowp    = (int*)alloc((size_t)(N + 1) * 4);
    int* incl    = (int*)alloc((size_t)N * 4);
    int* bsums   = (int*)alloc(512 * 4);
    int* ed      = (int*)alloc(((size_t)E + 4 * (size_t)N) * 4 + 512);
    unsigned short* hWs  = (unsigned short*)alloc((size_t)(N + 1) * HD * 2);
    unsigned short* hraw = (unsigned short*)alloc((size_t)N * HD * 2);
    float* ss    = (float*)alloc(3 * 128 * 4);
    unsigned* Wfb = (unsigned*)alloc(2 * HD * 32 * 4);
    float* cf    = (float*)alloc(2 * HD * 4);
    int* gcnt    = (int*)alloc((size_t)G * 4);
    (void)ws_size;

    float* pool = (float*)d_out;                      // [G,192]
    float* hbuf = (float*)d_out + (size_t)G * 192;    // [N,64] final h (fp32)

    hipMemsetAsync(deg, 0, zbytes, stream);

    int nb = (N + 255) / 256;
    int nslab = (E + FILL_SLAB - 1) / FILL_SLAB;
    k_deg<<<nslab * 8, 256, 0, stream>>>(dstA, deg, E);
    k_scan1<<<nb, 256, 0, stream>>>(deg, incl, bsums, dinv, (unsigned*)hWs, N);
    k_scan3<<<nb, 256, 0, stream>>>(rowp, deg, incl, bsums, ed, N, nb);
    k_fill<<<nslab * 8, 256, 0, stream>>>(srcA, dstA, rowp, cur, ed, batch, gcnt, E, N, G);

    const int AGG_BLOCKS = 512;                // 2 blocks/CU (66KB LDS) -> all co-resident
    const int NW = AGG_BLOCKS * 4;
    const int chunk = (N + NW - 1) / NW;       // 49 (must stay <= 63 for metadata pre-stage)
    const int ntiles = (N + 15) / 16;

    for (int l = 0; l < 3; l++) {
        if (l == 0)
            k_gemm2<1><<<1280, 256, 0, stream>>>(x, W[0], nullptr, dinv, hWs, N, ntiles);
        else
            k_gemm2<0><<<1280, 256, 0, stream>>>(hraw, Wfb + (size_t)(l - 1) * HD * 32,
                                                 cf + (l - 1) * HD, dinv, hWs, N, ntiles);
        void* outp = (l < 2) ? (void*)hraw : (void*)hbuf;
        k_agg<<<AGG_BLOCKS, 256, 0, stream>>>(rowp, ed, dinv, (const unsigned*)hWs,
                                              bias[l], batch, outp, (l < 2) ? 1 : 0,
                                              stats + l * 128, praw + (size_t)l * G * HD,
                                              N, chunk,
                                              gam[l], bet[l], ss + l * 128,
                                              (l < 2) ? W[l + 1] : nullptr,
                                              Wfb + (size_t)(l < 2 ? l : 0) * HD * 32,
                                              cf + (l < 2 ? l : 0) * HD,
                                              1.0f / (float)N, tickets + l);
    }
    int nquads = N * HD / 4;
    int nb1 = (nquads + 255) / 256;
    int nb2 = (G * 192 + 255) / 256;
    k_fin<<<nb1 + nb2, 256, 0, stream>>>(hbuf, ss, praw, gcnt, pool, nquads, G);
}

// Round 10
// 378.602 us; speedup vs baseline: 1.1525x; 1.1525x over previous
//
#include <hip/hip_runtime.h>

#define HD 64
#define BN_EPS 1e-5f

typedef unsigned int u32;
typedef __attribute__((ext_vector_type(4))) int i4;
typedef __attribute__((ext_vector_type(8))) short bfrag;
typedef __attribute__((ext_vector_type(4))) float ffrag;

__device__ __forceinline__ unsigned tobf(float x) {
    unsigned u = __float_as_uint(x);
    return (u + 0x7fffu + ((u >> 16) & 1u)) >> 16;
}
__device__ __forceinline__ float bf_lo(unsigned u) { return __uint_as_float(u << 16); }
__device__ __forceinline__ float bf_hi(unsigned u) { return __uint_as_float(u & 0xffff0000u); }

// ---------- CSR construction (rows padded to 8: slot0=self, pads->node N) ----------

#define FILL_SLAB 4096

// degree count + per-edge within-row rank, x4 vectorized (ext-vector NT loads/stores,
// 4 independent atomics in flight per thread)
__global__ void k_deg(const int* __restrict__ dst, int* __restrict__ deg,
                      int* __restrict__ rank, int E) {
    int e0 = (blockIdx.x * blockDim.x + threadIdx.x) * 4;
    if (e0 + 3 < E) {
        i4 d = __builtin_nontemporal_load((const i4*)(dst + e0));
        i4 r;
        r.x = atomicAdd(&deg[d.x], 1);
        r.y = atomicAdd(&deg[d.y], 1);
        r.z = atomicAdd(&deg[d.z], 1);
        r.w = atomicAdd(&deg[d.w], 1);
        __builtin_nontemporal_store(r, (i4*)(rank + e0));
    } else {
        for (int e = e0; e < E; e++) {
            int d = dst[e];
            rank[e] = atomicAdd(&deg[d], 1);
        }
    }
}

// inclusive scan of padded degree (256/block) + dinv + hWs zero-row init
__global__ void k_scan1(const int* __restrict__ deg, int* __restrict__ incl,
                        int* __restrict__ bsums, float* __restrict__ dinv,
                        unsigned* __restrict__ hWs, int N) {
    __shared__ int s[256];
    int tid = threadIdx.x;
    int i = blockIdx.x * 256 + tid;
    if (blockIdx.x == 0 && tid < 32) hWs[(size_t)N * 32 + tid] = 0u;  // zero row
    int d = (i < N) ? deg[i] : 0;
    int pd = (i < N) ? ((d + 8) & ~7) : 0;  // roundup(deg+1, 8)
    s[tid] = pd;
    __syncthreads();
    for (int off = 1; off < 256; off <<= 1) {
        int t = (tid >= off) ? s[tid - off] : 0;
        __syncthreads();
        s[tid] += t;
        __syncthreads();
    }
    if (i < N) {
        incl[i] = s[tid];
        dinv[i] = rsqrtf((float)(d + 1));
    }
    if (tid == 255) bsums[blockIdx.x] = s[255];
}

// rowp from incl + per-block prefix of bsums (reduction, no separate scan pass);
// also writes self edge into slot0 and pad slots -> N
__global__ void k_scan3(int* __restrict__ rowp, const int* __restrict__ deg,
                        const int* __restrict__ incl, const int* __restrict__ bsums,
                        int* __restrict__ ed, int N, int nb) {
    __shared__ float red[256];
    int tid = threadIdx.x;
    int b = blockIdx.x;
    float psum = 0.f;
    for (int t = tid; t < b; t += 256) psum += (float)bsums[t];
    red[tid] = psum;
    __syncthreads();
    for (int off = 128; off > 0; off >>= 1) {
        if (tid < off) red[tid] += red[tid + off];
        __syncthreads();
    }
    int bpre = (int)red[0];
    int i = b * 256 + tid;
    if (i < N) {
        int d = deg[i];
        int pd = (d + 8) & ~7;
        int rv = incl[i] - pd + bpre;  // exclusive global offset
        rowp[i] = rv;
        ed[rv] = i;  // self edge in slot 0
        for (int k = d + 1; k < pd; k++) ed[rv + k] = N;  // pads -> zero row
        if (i == N - 1) rowp[N] = rv + pd;
    }
}

// ---------- fused: XCD-partitioned CSR scatter (blocks < FB) + layer-0 MFMA gemm ----------
// Fill: 4 partitions ((dst>>12)&3), x4-vectorized ext-vector NT loads of dst/src/rank,
// 4 independent scattered ed writes in flight per thread (fixes VGPR=8 MLP starvation).
// No atomic: rank precomputed in k_deg. Per-graph counts fused (unique gid).
// Gemm blocks (>= FB): hWs[i][f] = bf16( dinv[i]*(sum_k x[i][k]*W0[f][k]) ), fp32 input.
// Both sides depend only on scan outputs (rowp / dinv) -> safe to co-launch;
// gemm0's compute rides under fill's latency-bound scatter.
__global__ __launch_bounds__(256) void k_fg0(const int* __restrict__ src,
                                             const int* __restrict__ dst,
                                             const int* __restrict__ rank,
                                             const int* __restrict__ rowp,
                                             int* __restrict__ ed,
                                             const int* __restrict__ batch,
                                             int* __restrict__ cnt, int E, int N, int G,
                                             int FB,
                                             const float* __restrict__ x,
                                             const float* __restrict__ W,
                                             const float* __restrict__ dinv,
                                             unsigned short* __restrict__ hWs,
                                             int ntiles, int gemmWaves) {
    int tid = threadIdx.x;
    if ((int)blockIdx.x < FB) {
        // ---- fill ----
        int gid = blockIdx.x * 256 + tid;
        if (gid < G) {
            int g = gid;
            int lo = 0, hi = N;
            while (lo < hi) { int mid = (lo + hi) >> 1; if (batch[mid] < g) lo = mid + 1; else hi = mid; }
            int lo2 = lo, hi2 = N;
            while (lo2 < hi2) { int mid = (lo2 + hi2) >> 1; if (batch[mid] < g + 1) lo2 = mid + 1; else hi2 = mid; }
            cnt[g] = lo2 - lo;
        }
        int part = blockIdx.x & 3;
        int base = (blockIdx.x >> 2) * FILL_SLAB;
        int end = min(base + FILL_SLAB, E);
        for (int e = base + tid * 4; e < end; e += 1024) {
            if (e + 3 < end) {
                i4 d = __builtin_nontemporal_load((const i4*)(dst + e));
                i4 s = __builtin_nontemporal_load((const i4*)(src + e));
                i4 r = __builtin_nontemporal_load((const i4*)(rank + e));
                if (((d.x >> 12) & 3) == part) ed[rowp[d.x] + 1 + r.x] = s.x;
                if (((d.y >> 12) & 3) == part) ed[rowp[d.y] + 1 + r.y] = s.y;
                if (((d.z >> 12) & 3) == part) ed[rowp[d.z] + 1 + r.z] = s.z;
                if (((d.w >> 12) & 3) == part) ed[rowp[d.w] + 1 + r.w] = s.w;
            } else {
                for (int ee = e; ee < end; ee++) {
                    int d = dst[ee];
                    if (((d >> 12) & 3) == part) ed[rowp[d] + 1 + rank[ee]] = src[ee];
                }
            }
        }
        return;
    }
    // ---- gemm0 (fp32 input) ----
    int lane = tid & 63;
    int m = lane & 15, quad = lane >> 4;
    bfrag wf[4][2];
#pragma unroll
    for (int ft = 0; ft < 4; ft++)
#pragma unroll
        for (int kf = 0; kf < 2; kf++) {
            const float4* p4 = (const float4*)(W + (ft * 16 + m) * HD + kf * 32 + quad * 8);
            float4 x0 = p4[0], x1 = p4[1];
            union { unsigned u[4]; bfrag b; } r;
            r.u[0] = tobf(x0.x) | (tobf(x0.y) << 16);
            r.u[1] = tobf(x0.z) | (tobf(x0.w) << 16);
            r.u[2] = tobf(x1.x) | (tobf(x1.y) << 16);
            r.u[3] = tobf(x1.z) | (tobf(x1.w) << 16);
            wf[ft][kf] = r.b;
        }
    int wid = (((int)blockIdx.x - FB) * 256 + tid) >> 6;
    for (int tile = wid; tile < ntiles; tile += gemmWaves) {
        int arow = min(tile * 16 + m, N - 1);
        const float4* p4 = (const float4*)(x + (size_t)arow * HD + quad * 8);
        float4 x0 = p4[0], x1 = p4[1], y0 = p4[8], y1 = p4[9];
        union { unsigned u[4]; bfrag b; } r0, r1;
        r0.u[0] = tobf(x0.x) | (tobf(x0.y) << 16);
        r0.u[1] = tobf(x0.z) | (tobf(x0.w) << 16);
        r0.u[2] = tobf(x1.x) | (tobf(x1.y) << 16);
        r0.u[3] = tobf(x1.z) | (tobf(x1.w) << 16);
        r1.u[0] = tobf(y0.x) | (tobf(y0.y) << 16);
        r1.u[1] = tobf(y0.z) | (tobf(y0.w) << 16);
        r1.u[2] = tobf(y1.x) | (tobf(y1.y) << 16);
        r1.u[3] = tobf(y1.z) | (tobf(y1.w) << 16);
        bfrag a0 = r0.b, a1 = r1.b;
        ffrag acc[4];
#pragma unroll
        for (int ft = 0; ft < 4; ft++) {
            acc[ft] = (ffrag){0.f, 0.f, 0.f, 0.f};
            acc[ft] = __builtin_amdgcn_mfma_f32_16x16x32_bf16(a0, wf[ft][0], acc[ft], 0, 0, 0);
            acc[ft] = __builtin_amdgcn_mfma_f32_16x16x32_bf16(a1, wf[ft][1], acc[ft], 0, 0, 0);
        }
        int r0n = tile * 16 + quad * 4;
        float dv[4];
#pragma unroll
        for (int r = 0; r < 4; r++) dv[r] = dinv[min(r0n + r, N - 1)];
#pragma unroll
        for (int ft = 0; ft < 4; ft++)
#pragma unroll
            for (int r = 0; r < 4; r++) {
                int nrow = r0n + r;
                if (nrow < N) {
                    float v = acc[ft][r] * dv[r];
                    hWs[(size_t)nrow * HD + ft * 16 + m] = (unsigned short)tobf(v);
                }
            }
    }
}

// ---------- MFMA gemm (layers 1,2): hWs[i][f] = bf16( dinv[i]*(sum_k A[i][k]*W[f][k] + cb[f]) ) ----------
__global__ __launch_bounds__(256) void k_gemm2(const void* __restrict__ Aptr,
                                               const void* __restrict__ Wptr,
                                               const float* __restrict__ cb,
                                               const float* __restrict__ dinv,
                                               unsigned short* __restrict__ hWs,
                                               int N, int ntiles) {
    int lane = threadIdx.x & 63;
    int m = lane & 15, quad = lane >> 4;
    bfrag wf[4][2];
    const unsigned short* W = (const unsigned short*)Wptr;
#pragma unroll
    for (int ft = 0; ft < 4; ft++)
#pragma unroll
        for (int kf = 0; kf < 2; kf++)
            wf[ft][kf] = *(const bfrag*)(W + (ft * 16 + m) * HD + kf * 32 + quad * 8);
    float cbv[4];
#pragma unroll
    for (int ft = 0; ft < 4; ft++) cbv[ft] = cb[ft * 16 + m];

    int wid = (blockIdx.x * blockDim.x + threadIdx.x) >> 6;
    int nw = (gridDim.x * blockDim.x) >> 6;
    for (int tile = wid; tile < ntiles; tile += nw) {
        int arow = min(tile * 16 + m, N - 1);
        const unsigned short* p = (const unsigned short*)Aptr + (size_t)arow * HD + quad * 8;
        bfrag a0 = *(const bfrag*)p;
        bfrag a1 = *(const bfrag*)(p + 32);
        ffrag acc[4];
#pragma unroll
        for (int ft = 0; ft < 4; ft++) {
            acc[ft] = (ffrag){0.f, 0.f, 0.f, 0.f};
            acc[ft] = __builtin_amdgcn_mfma_f32_16x16x32_bf16(a0, wf[ft][0], acc[ft], 0, 0, 0);
            acc[ft] = __builtin_amdgcn_mfma_f32_16x16x32_bf16(a1, wf[ft][1], acc[ft], 0, 0, 0);
        }
        int r0n = tile * 16 + quad * 4;
        float dv[4];
#pragma unroll
        for (int r = 0; r < 4; r++) dv[r] = dinv[min(r0n + r, N - 1)];
#pragma unroll
        for (int ft = 0; ft < 4; ft++)
#pragma unroll
            for (int r = 0; r < 4; r++) {
                int nrow = r0n + r;
                if (nrow < N) {
                    float v = (acc[ft][r] + cbv[ft]) * dv[r];
                    hWs[(size_t)nrow * HD + ft * 16 + m] = (unsigned short)tobf(v);
                }
            }
    }
}

// ---------- aggregation (r6-proven): 64-slot stages (8x global_load_lds, 8KB), pad-8 ----------
// Double-buffered; node metadata pre-staged one-node-per-lane (chunk <= 63).
// Consume: 8-slot groups, lane=hf*32+m handles features (2m,2m+1), halves
// combined at node end via shfl_xor(32). Conflict-free LDS reads.
// LDS 66KB/block -> 2 blocks/CU. Measured 54 us/layer (structural gather ceiling).
__global__ __launch_bounds__(256) void k_agg(const int* __restrict__ rowp,
                                             const int* __restrict__ ed,
                                             const float* __restrict__ dinv,
                                             const unsigned* __restrict__ hWs,
                                             const float* __restrict__ bias,
                                             const int* __restrict__ batch,
                                             void* __restrict__ outp, int outBf,
                                             float* __restrict__ stats,
                                             float* __restrict__ praw,
                                             int N, int chunk,
                                             const float* __restrict__ gam,
                                             const float* __restrict__ bet,
                                             float* __restrict__ ss,
                                             const float* __restrict__ Wnext,
                                             unsigned* __restrict__ Wfb,
                                             float* __restrict__ cf,
                                             float invN, int* __restrict__ ticket) {
    __shared__ u32 sbuf[4][2][2048];   // per-wave double-buffered stage: 64 slots x 32 words
    int tid = threadIdx.x;
    int lane = tid & 63;
    int hf = lane >> 5;
    int m = lane & 31;
    int lsel = lane >> 3;   // slot sub-index within an 8-slot gather
    int fsel = lane & 7;    // 16B sub-row handled by this lane
    int wv = tid >> 6;
    int wid = blockIdx.x * 4 + wv;
    int i0 = wid * chunk, i1 = min(i0 + chunk, N);
    const uint4* hW4 = (const uint4*)hWs;
    float b0 = bias[2 * m], b1 = bias[2 * m + 1];
    float bs0 = 0.f, bs1 = 0.f, bq0 = 0.f, bq1 = 0.f;
    int curb = -1;
    float p0 = 0.f, p1 = 0.f;
    if (i0 < N) {
        // pre-stage per-node metadata: lane l holds node i0+l (chunk <= 63)
        int idx = i0 + lane;
        int rowv = rowp[min(idx, N)];
        float dinvv = dinv[min(idx, N - 1)];
        int batchv = batch[min(idx, N - 1)];
        int s0g = __shfl(rowv, 0);
        int send = __shfl(rowv, i1 - i0);
        int i = i0, ln = 0;
        int rem = (__shfl(rowv, 1) - s0g) >> 3;  // 8-slot groups left in node i
        float acc0 = 0.f, acc1 = 0.f;
        int nst = (send - s0g + 63) >> 6;        // 64-slot stages
        int sb = s0g;
        // prologue: ids + gathers for stage 0 (one id per lane)
        int eidx;
        { int id = sb + lane; eidx = (id < send) ? __builtin_nontemporal_load(&ed[id]) : N; }
#pragma unroll
        for (int j = 0; j < 8; j++) {
            int sj = __shfl(eidx, j * 8 + lsel);
            __builtin_amdgcn_global_load_lds(
                (const __attribute__((address_space(1))) u32*)(hW4 + (size_t)sj * 8 + fsel),
                (__attribute__((address_space(3))) u32*)(&sbuf[wv][0][j * 256]),
                16, 0, 0);
        }
        int eidxN = N;
        if (nst > 1) { int id = sb + 64 + lane; eidxN = (id < send) ? __builtin_nontemporal_load(&ed[id]) : N; }
        for (int t = 0; t < nst; t++) {
            int cb = t & 1;
            // stage t's DMA (and eidxN) complete; compiler must not hoist LDS reads above
            asm volatile("s_waitcnt vmcnt(0)" ::: "memory");
            __builtin_amdgcn_sched_barrier(0);
            if (t + 1 < nst) {
#pragma unroll
                for (int j = 0; j < 8; j++) {
                    int sj = __shfl(eidxN, j * 8 + lsel);
                    __builtin_amdgcn_global_load_lds(
                        (const __attribute__((address_space(1))) u32*)(hW4 + (size_t)sj * 8 + fsel),
                        (__attribute__((address_space(3))) u32*)(&sbuf[wv][cb ^ 1][j * 256]),
                        16, 0, 0);
                }
                if (t + 2 < nst) { int id = sb + 128 + lane; eidxN = (id < send) ? __builtin_nontemporal_load(&ed[id]) : N; }
            }
            const u32* cur = &sbuf[wv][cb][0];
            int ng = min(8, (send - sb) >> 3);   // 8-slot groups this stage
            for (int g = 0; g < ng; g++) {
                u32 u[4];
#pragma unroll
                for (int tt = 0; tt < 4; tt++)
                    u[tt] = cur[(g * 8 + hf + 2 * tt) * 32 + m];
#pragma unroll
                for (int tt = 0; tt < 4; tt++) { acc0 += bf_lo(u[tt]); acc1 += bf_hi(u[tt]); }
                if (--rem == 0) {  // node i complete (wave-uniform)
                    float s0 = acc0 + __shfl_xor(acc0, 32);
                    float s1 = acc1 + __shfl_xor(acc1, 32);
                    float di = __shfl(dinvv, ln);   // register shuffle, no load
                    int b = __shfl(batchv, ln);
                    float h0 = fmaxf(fmaf(di, s0, b0), 0.f);
                    float h1 = fmaxf(fmaf(di, s1, b1), 0.f);
                    if (lane < 32) {
                        if (outBf) ((unsigned*)outp)[(size_t)i * 32 + m] = tobf(h0) | (tobf(h1) << 16);
                        else ((float2*)outp)[(size_t)i * 32 + m] = make_float2(h0, h1);
                        bs0 += h0; bs1 += h1;
                        bq0 = fmaf(h0, h0, bq0); bq1 = fmaf(h1, h1, bq1);
                        if (b != curb) {
                            if (curb >= 0) {
                                atomicAdd(&praw[(size_t)curb * HD + 2 * m], p0);
                                atomicAdd(&praw[(size_t)curb * HD + 2 * m + 1], p1);
                            }
                            curb = b; p0 = h0; p1 = h1;
                        } else { p0 += h0; p1 += h1; }
                    }
                    i++; ln++;
                    rem = (i < i1) ? ((__shfl(rowv, ln + 1) - __shfl(rowv, ln)) >> 3)
                                   : 0x3fffffff;  // sentinel: never triggers past range
                    acc0 = 0.f; acc1 = 0.f;
                }
            }
            sb += 64;
        }
    }
    if (lane < 32 && curb >= 0) {
        atomicAdd(&praw[(size_t)curb * HD + 2 * m], p0);
        atomicAdd(&praw[(size_t)curb * HD + 2 * m + 1], p1);
    }
    __shared__ float r1s[4][HD], r2s[4][HD];
    if (lane < 32) {
        r1s[wv][2 * m] = bs0; r1s[wv][2 * m + 1] = bs1;
        r2s[wv][2 * m] = bq0; r2s[wv][2 * m + 1] = bq1;
    }
    __syncthreads();
    if (tid < HD) {
        atomicAdd(&stats[tid], r1s[0][tid] + r1s[1][tid] + r1s[2][tid] + r1s[3][tid]);
        atomicAdd(&stats[HD + tid], r2s[0][tid] + r2s[1][tid] + r2s[2][tid] + r2s[3][tid]);
    }
    // ---- last block: BN finalize + fold into next layer's weights ----
    __shared__ int lastFlag;
    __syncthreads();  // drain this block's stats atomics
    if (tid == 0) {
        __threadfence();
        lastFlag = (atomicAdd(ticket, 1) == (int)gridDim.x - 1) ? 1 : 0;
    }
    __syncthreads();
    if (lastFlag) {
        __shared__ float lss[128];
        __shared__ float cpart[HD][4];
        if (tid < HD) {
            float s1v = atomicAdd(&stats[tid], 0.f);       // coherent read
            float s2v = atomicAdd(&stats[HD + tid], 0.f);
            float mean = s1v * invN;
            float var = s2v * invN - mean * mean;
            float sc = gam[tid] * rsqrtf(var + BN_EPS);
            float sh = bet[tid] - mean * sc;
            ss[tid] = sc; ss[64 + tid] = sh;
            lss[tid] = sc; lss[64 + tid] = sh;
        }
        __syncthreads();
        if (Wnext) {   // 256 threads: 64 rows x 4 partials, float4 weight loads
            int r = tid >> 2, qs = (tid & 3) * 8;
            const float4* W4 = (const float4*)(Wnext + r * HD + 2 * qs);
            float c = 0.f;
#pragma unroll
            for (int t = 0; t < 4; t++) {
                float4 w = W4[t];
                int q = qs + 2 * t;
                Wfb[r * 32 + q]     = tobf(w.x * lss[2 * q])     | (tobf(w.y * lss[2 * q + 1]) << 16);
                Wfb[r * 32 + q + 1] = tobf(w.z * lss[2 * q + 2]) | (tobf(w.w * lss[2 * q + 3]) << 16);
                c = fmaf(lss[64 + 2 * q], w.x, c);
                c = fmaf(lss[64 + 2 * q + 1], w.y, c);
                c = fmaf(lss[64 + 2 * q + 2], w.z, c);
                c = fmaf(lss[64 + 2 * q + 3], w.w, c);
            }
            cpart[r][tid & 3] = c;
            __syncthreads();
            if (tid < HD)
                cf[tid] = cpart[tid][0] + cpart[tid][1] + cpart[tid][2] + cpart[tid][3];
        }
    }
}

// fused: normalize final h in place (float4) + pool finalize
__global__ __launch_bounds__(256) void k_fin(float* __restrict__ h,
                                             const float* __restrict__ ss_all,
                                             const float* __restrict__ praw,
                                             const int* __restrict__ cnt,
                                             float* __restrict__ pool,
                                             int nquads, int G) {
    int nb1 = (nquads + 255) >> 8;
    if ((int)blockIdx.x < nb1) {
        int idx = blockIdx.x * 256 + threadIdx.x;
        if (idx >= nquads) return;
        const float* ss = ss_all + 2 * 128;
        float4* h4 = (float4*)h;
        float4 v = h4[idx];
        int f0 = (idx * 4) & 63;
        v.x = fmaf(v.x, ss[f0 + 0], ss[64 + f0 + 0]);
        v.y = fmaf(v.y, ss[f0 + 1], ss[64 + f0 + 1]);
        v.z = fmaf(v.z, ss[f0 + 2], ss[64 + f0 + 2]);
        v.w = fmaf(v.w, ss[f0 + 3], ss[64 + f0 + 3]);
        h4[idx] = v;
    } else {
        int idx = (blockIdx.x - nb1) * 256 + threadIdx.x;
        if (idx >= G * 192) return;
        int g = idx / 192;
        int r = idx - g * 192;
        int l = r >> 6;
        int f = r & 63;
        const float* ss = ss_all + l * 128;
        float v = praw[((size_t)l * G + g) * HD + f];
        pool[idx] = fmaf(ss[f], v, (float)cnt[g] * ss[64 + f]);
    }
}

extern "C" void kernel_launch(void* const* d_in, const int* in_sizes, int n_in,
                              void* d_out, int out_size, void* d_ws, size_t ws_size,
                              hipStream_t stream) {
    const int N = in_sizes[0] / HD;             // 100000
    const int E = in_sizes[1] / 2;              // 1000000
    const int G = (out_size - N * HD) / 192;    // 512

    const float* x = (const float*)d_in[0];
    const int* ei = (const int*)d_in[1];
    const int* srcA = ei;
    const int* dstA = ei + E;
    const int* batch = (const int*)d_in[2];
    const float* W[3]    = {(const float*)d_in[3], (const float*)d_in[7],  (const float*)d_in[11]};
    const float* bias[3] = {(const float*)d_in[4], (const float*)d_in[8],  (const float*)d_in[12]};
    const float* gam[3]  = {(const float*)d_in[5], (const float*)d_in[9],  (const float*)d_in[13]};
    const float* bet[3]  = {(const float*)d_in[6], (const float*)d_in[10], (const float*)d_in[14]};

    char* ws = (char*)d_ws;
    size_t off = 0;
    auto alloc = [&](size_t bytes) -> void* {
        void* p = ws + off;
        off = (off + bytes + 255) & ~(size_t)255;
        return p;
    };
    // zero-region (single memset): deg, stats, tickets, praw
    int* deg     = (int*)alloc((size_t)N * 4);
    float* stats = (float*)alloc(3 * 128 * 4);
    int* tickets = (int*)alloc(3 * 4);
    float* praw  = (float*)alloc((size_t)3 * G * HD * 4);
    size_t zbytes = off;
    int* rank    = (int*)alloc((size_t)E * 4);
    float* dinv  = (float*)alloc((size_t)N * 4);
    int* rowp    = (int*)alloc((size_t)(N + 1) * 4);
    int* incl    = (int*)alloc((size_t)N * 4);
    int* bsums   = (int*)alloc(512 * 4);
    int* ed      = (int*)alloc(((size_t)E + 8 * (size_t)N) * 4 + 512);
    unsigned short* hWs  = (unsigned short*)alloc((size_t)(N + 1) * HD * 2);
    unsigned short* hraw = (unsigned short*)alloc((size_t)N * HD * 2);
    float* ss    = (float*)alloc(3 * 128 * 4);
    unsigned* Wfb = (unsigned*)alloc(2 * HD * 32 * 4);
    float* cf    = (float*)alloc(2 * HD * 4);
    int* gcnt    = (int*)alloc((size_t)G * 4);
    (void)ws_size;

    float* pool = (float*)d_out;                      // [G,192]
    float* hbuf = (float*)d_out + (size_t)G * 192;    // [N,64] final h (fp32)

    hipMemsetAsync(deg, 0, zbytes, stream);

    int nb = (N + 255) / 256;
    k_deg<<<(E / 4 + 255) / 256, 256, 0, stream>>>(dstA, deg, rank, E);
    k_scan1<<<nb, 256, 0, stream>>>(deg, incl, bsums, dinv, (unsigned*)hWs, N);
    k_scan3<<<nb, 256, 0, stream>>>(rowp, deg, incl, bsums, ed, N, nb);

    const int AGG_BLOCKS = 512;                // 2 blocks/CU (66KB LDS) -> all co-resident
    const int NW = AGG_BLOCKS * 4;
    const int chunk = (N + NW - 1) / NW;       // 49 (must stay <= 63 for metadata pre-stage)
    const int ntiles = (N + 15) / 16;
    const int GEMM_BLOCKS = 640;
    const int gemmWaves = GEMM_BLOCKS * 4;

    // fused fill + gemm0
    int nslab = (E + FILL_SLAB - 1) / FILL_SLAB;
    int FB = nslab * 4;
    k_fg0<<<FB + GEMM_BLOCKS, 256, 0, stream>>>(srcA, dstA, rank, rowp, ed, batch, gcnt,
                                                E, N, G, FB,
                                                x, W[0], dinv, hWs, ntiles, gemmWaves);

    for (int l = 0; l < 3; l++) {
        if (l > 0)
            k_gemm2<<<GEMM_BLOCKS, 256, 0, stream>>>(hraw, Wfb + (size_t)(l - 1) * HD * 32,
                                                     cf + (l - 1) * HD, dinv, hWs, N, ntiles);
        void* outp = (l < 2) ? (void*)hraw : (void*)hbuf;
        k_agg<<<AGG_BLOCKS, 256, 0, stream>>>(rowp, ed, dinv, (const unsigned*)hWs,
                                              bias[l], batch, outp, (l < 2) ? 1 : 0,
                                              stats + l * 128, praw + (size_t)l * G * HD,
                                              N, chunk,
                                              gam[l], bet[l], ss + l * 128,
                                              (l < 2) ? W[l + 1] : nullptr,
                                              Wfb + (size_t)(l < 2 ? l : 0) * HD * 32,
                                              cf + (l < 2 ? l : 0) * HD,
                                              1.0f / (float)N, tickets + l);
    }
    int nquads = N * HD / 4;
    int nb1 = (nquads + 255) / 256;
    int nb2 = (G * 192 + 255) / 256;
    k_fin<<<nb1 + nb2, 256, 0, stream>>>(hbuf, ss, praw, gcnt, pool, nquads, G);
}